// Round 1
// baseline (877.533 us; speedup 1.0000x reference)
//
#include <hip/hip_runtime.h>

#define D_MODEL 2048
#define NHEADS 16
#define DHEAD 128
#define TSEQ 2048
#define BATCH 4
#define MROWS (BATCH*TSEQ)   // 8192
#define NQKV (3*D_MODEL)     // 6144
#define BH (BATCH*NHEADS)    // 64

typedef __attribute__((ext_vector_type(4))) float f32x4;
typedef __attribute__((ext_vector_type(8))) __bf16 bf16x8;
typedef __attribute__((ext_vector_type(4))) unsigned int u32x4;

__device__ inline unsigned short f2bf(float f) {
  union { float f; unsigned u; } v; v.f = f;
  unsigned r = (v.u + 0x7fffu + ((v.u >> 16) & 1u)) >> 16;
  return (unsigned short)r;
}
__device__ inline float bf2f(unsigned short h) {
  union { unsigned u; float f; } v; v.u = ((unsigned)h) << 16; return v.f;
}

// ---------------- fp32 -> bf16 convert (vectorized, G13) ----------------
__global__ __launch_bounds__(256) void cvt_bf16(const float* __restrict__ in,
                                                unsigned short* __restrict__ out, int n) {
  int i = (blockIdx.x * 256 + threadIdx.x) * 8;
  if (i >= n) return;
  float4 a = *(const float4*)(in + i);
  float4 b = *(const float4*)(in + i + 4);
  union { unsigned short s[8]; u32x4 v; } r;
  r.s[0] = f2bf(a.x); r.s[1] = f2bf(a.y); r.s[2] = f2bf(a.z); r.s[3] = f2bf(a.w);
  r.s[4] = f2bf(b.x); r.s[5] = f2bf(b.y); r.s[6] = f2bf(b.z); r.s[7] = f2bf(b.w);
  *(u32x4*)(out + i) = r.v;
}

// ---------------- w [K][N] fp32 -> wT [N][K] bf16 ----------------
__global__ __launch_bounds__(256) void transw(const float* __restrict__ w,
                                              unsigned short* __restrict__ wt, int K, int N) {
  __shared__ float tile[32][33];
  int n0 = blockIdx.x * 32, k0 = blockIdx.y * 32;
  int x = threadIdx.x & 31, y = threadIdx.x >> 5;
  #pragma unroll
  for (int j = 0; j < 4; ++j)
    tile[y + j * 8][x] = w[(size_t)(k0 + y + j * 8) * N + n0 + x];
  __syncthreads();
  #pragma unroll
  for (int j = 0; j < 4; ++j)
    wt[(size_t)(n0 + y + j * 8) * K + k0 + x] = f2bf(tile[x][y + j * 8]);
}

// ---------------- RoPE cos/sin table: tab[t][f], f in [0,64) ----------------
__global__ void rope_table(float2* __restrict__ tab) {
  int t = blockIdx.x, f = threadIdx.x;
  float inv = __expf(-0.14391156831212787f * (float)f); // ln(10000)/64
  float ang = (float)t * inv;
  tab[t * 64 + f] = make_float2(cosf(ang), sinf(ang));
}

// ---------------- apply rotate-half RoPE in place on [BH][T][128] bf16 ----------------
__global__ __launch_bounds__(256) void rope_apply(unsigned short* __restrict__ X,
                                                  const float2* __restrict__ tab) {
  int row = blockIdx.x * 4 + (threadIdx.x >> 6);
  int f = threadIdx.x & 63;
  int t = row & (TSEQ - 1);
  unsigned short* p = X + (size_t)row * DHEAD;
  float2 cs = tab[t * 64 + f];
  float x1 = bf2f(p[f]), x2 = bf2f(p[f + 64]);
  p[f]      = f2bf(x1 * cs.x - x2 * cs.y);
  p[f + 64] = f2bf(x2 * cs.x + x1 * cs.y);
}

// ---------------- GEMM: C[M][N] = A[M][K] @ Bt[N][K]^T + bias ----------------
// MODE 0: scatter to Qb/Kb (head-major) and VTb (transposed V). MODE 1: fp32 out.
template<int MODE>
__global__ __launch_bounds__(256) void gemm_bt(
    const unsigned short* __restrict__ A,
    const unsigned short* __restrict__ Bt,
    const float* __restrict__ bias,
    int M, int N, int K,
    unsigned short* __restrict__ Qb,
    unsigned short* __restrict__ Kb,
    unsigned short* __restrict__ VTb,
    float* __restrict__ outF)
{
  // padded stride 72 elems (144 B, 16B-aligned): rows 0..7 hit distinct bank
  // groups (4*r mod 32), rows 8..15 alias 2-way = free (m136)
  __shared__ unsigned short Asm_[128 * 72];
  __shared__ unsigned short Bsm_[128 * 72];
  int tid = threadIdx.x;
  int wid = tid >> 6, lane = tid & 63;
  int wm = wid >> 1, wn = wid & 1;
  int l15 = lane & 15, l16 = lane >> 4;
  int row0 = blockIdx.y * 128, col0 = blockIdx.x * 128;
  f32x4 acc[4][4] = {};

  for (int k0 = 0; k0 < K; k0 += 64) {
    #pragma unroll
    for (int c = 0; c < 4; ++c) {
      int e = (c * 256 + tid) * 8;
      int r = e >> 6, cc = e & 63;
      *(u32x4*)&Asm_[r * 72 + cc] = *(const u32x4*)&A[(size_t)(row0 + r) * K + k0 + cc];
      *(u32x4*)&Bsm_[r * 72 + cc] = *(const u32x4*)&Bt[(size_t)(col0 + r) * K + k0 + cc];
    }
    __syncthreads();
    #pragma unroll
    for (int kk = 0; kk < 2; ++kk) {
      bf16x8 av[4], bv[4];
      #pragma unroll
      for (int m = 0; m < 4; ++m)
        av[m] = *(const bf16x8*)&Asm_[(wm * 64 + m * 16 + l15) * 72 + kk * 32 + l16 * 8];
      #pragma unroll
      for (int n = 0; n < 4; ++n)
        bv[n] = *(const bf16x8*)&Bsm_[(wn * 64 + n * 16 + l15) * 72 + kk * 32 + l16 * 8];
      #pragma unroll
      for (int m = 0; m < 4; ++m)
        #pragma unroll
        for (int n = 0; n < 4; ++n)
          acc[m][n] = __builtin_amdgcn_mfma_f32_16x16x32_bf16(av[m], bv[n], acc[m][n], 0, 0, 0);
    }
    __syncthreads();
  }

  #pragma unroll
  for (int m = 0; m < 4; ++m) {
    #pragma unroll
    for (int n = 0; n < 4; ++n) {
      int col = col0 + wn * 64 + n * 16 + l15;
      float bs = bias[col];
      #pragma unroll
      for (int r = 0; r < 4; ++r) {
        int row = row0 + wm * 64 + m * 16 + l16 * 4 + r;  // verified C layout (m89/m91)
        float val = acc[m][n][r] + bs;
        if (MODE == 0) {
          int which = col >> 11;            // 0=q 1=k 2=v (uniform per block)
          int rem = col & 2047;
          int h = rem >> 7, dh = rem & 127;
          int b = row >> 11, t = row & 2047;
          int bh = b * NHEADS + h;
          if (which == 0)      Qb[((size_t)bh * TSEQ + t) * DHEAD + dh] = f2bf(val);
          else if (which == 1) Kb[((size_t)bh * TSEQ + t) * DHEAD + dh] = f2bf(val);
          else                 VTb[((size_t)bh * DHEAD + dh) * TSEQ + t] = f2bf(val);
        } else {
          outF[(size_t)row * N + col] = val;
        }
      }
    }
  }
}

// ---------------- causal flash attention ----------------
// grid (T/64, BH), 4 waves: wave w owns q rows [q0+16w, +16). KVBLK=32.
__global__ __launch_bounds__(256) void attn_fwd(
    const unsigned short* __restrict__ Qb,
    const unsigned short* __restrict__ Kb,
    const unsigned short* __restrict__ VTb,
    unsigned short* __restrict__ ctx)
{
  __shared__ unsigned short Ksm[32 * 136];   // [kv][d] padded 128->136
  __shared__ unsigned short Vsm[128 * 40];   // [d][kv] padded 32->40
  __shared__ unsigned short Psm[4][16 * 40]; // per-wave P, padded
  int qblk = blockIdx.x, bh = blockIdx.y;
  int tid = threadIdx.x, wid = tid >> 6, lane = tid & 63;
  int l15 = lane & 15, l16 = lane >> 4;
  int q0 = qblk * 64;
  int qw = q0 + wid * 16;
  const float scale = 0.08838834764831845f;  // 1/sqrt(128)

  bf16x8 qf[4];
  const unsigned short* Qrow = Qb + ((size_t)bh * TSEQ + qw + l15) * DHEAD;
  #pragma unroll
  for (int kk = 0; kk < 4; ++kk)
    qf[kk] = *(const bf16x8*)&Qrow[kk * 32 + l16 * 8];

  f32x4 accO[8] = {};
  float mrow[4], lrow[4];
  #pragma unroll
  for (int r = 0; r < 4; ++r) { mrow[r] = -1e30f; lrow[r] = 0.f; }

  int nt = qblk * 2 + 2;
  for (int jt = 0; jt < nt; ++jt) {
    __syncthreads();
    #pragma unroll
    for (int c = 0; c < 2; ++c) {
      int e = (c * 256 + tid) * 8;
      int tr = e >> 7, tc = e & 127;
      *(u32x4*)&Ksm[tr * 136 + tc] =
          *(const u32x4*)&Kb[((size_t)bh * TSEQ + jt * 32 + tr) * DHEAD + tc];
      int vr = e >> 5, vc = e & 31;
      *(u32x4*)&Vsm[vr * 40 + vc] =
          *(const u32x4*)&VTb[((size_t)bh * DHEAD + vr) * TSEQ + jt * 32 + vc];
    }
    __syncthreads();

    f32x4 sfr[2] = {};
    #pragma unroll
    for (int n = 0; n < 2; ++n)
      #pragma unroll
      for (int kk = 0; kk < 4; ++kk) {
        bf16x8 kf = *(const bf16x8*)&Ksm[(n * 16 + l15) * 136 + kk * 32 + l16 * 8];
        sfr[n] = __builtin_amdgcn_mfma_f32_16x16x32_bf16(qf[kk], kf, sfr[n], 0, 0, 0);
      }

    // wave-parallel online softmax (16-lane groups)
    #pragma unroll
    for (int r = 0; r < 4; ++r) {
      int qg = qw + l16 * 4 + r;
      float s0 = sfr[0][r] * scale;
      float s1 = sfr[1][r] * scale;
      int kv0 = jt * 32 + l15;
      if (kv0 > qg)      s0 = -1e30f;
      if (kv0 + 16 > qg) s1 = -1e30f;
      float v = fmaxf(s0, s1);
      #pragma unroll
      for (int off = 1; off < 16; off <<= 1) v = fmaxf(v, __shfl_xor(v, off));
      float mnew = fmaxf(mrow[r], v);
      float alpha = __expf(mrow[r] - mnew);
      float p0 = __expf(s0 - mnew), p1 = __expf(s1 - mnew);
      float ps = p0 + p1;
      #pragma unroll
      for (int off = 1; off < 16; off <<= 1) ps += __shfl_xor(ps, off);
      lrow[r] = lrow[r] * alpha + ps;
      mrow[r] = mnew;
      #pragma unroll
      for (int n = 0; n < 8; ++n) accO[n][r] *= alpha;
      int qrow = l16 * 4 + r;
      Psm[wid][qrow * 40 + l15]      = f2bf(p0);
      Psm[wid][qrow * 40 + l15 + 16] = f2bf(p1);
    }

    bf16x8 pf = *(const bf16x8*)&Psm[wid][l15 * 40 + l16 * 8];
    #pragma unroll
    for (int n = 0; n < 8; ++n) {
      bf16x8 vf = *(const bf16x8*)&Vsm[(n * 16 + l15) * 40 + l16 * 8];
      accO[n] = __builtin_amdgcn_mfma_f32_16x16x32_bf16(pf, vf, accO[n], 0, 0, 0);
    }
  }

  int b = bh >> 4, h = bh & 15;
  #pragma unroll
  for (int r = 0; r < 4; ++r) {
    float inv = 1.0f / lrow[r];
    int t = qw + l16 * 4 + r;
    size_t base = ((size_t)b * TSEQ + t) * D_MODEL + h * DHEAD;
    #pragma unroll
    for (int n = 0; n < 8; ++n)
      ctx[base + n * 16 + l15] = f2bf(accO[n][r] * inv);
  }
}

extern "C" void kernel_launch(void* const* d_in, const int* in_sizes, int n_in,
                              void* d_out, int out_size, void* d_ws, size_t ws_size,
                              hipStream_t stream)
{
  const float* x     = (const float*)d_in[0];
  const float* w_qkv = (const float*)d_in[1];
  const float* b_qkv = (const float*)d_in[2];
  const float* w_out = (const float*)d_in[3];
  const float* b_out = (const float*)d_in[4];
  float* out = (float*)d_out;

  unsigned short* xb    = (unsigned short*)d_ws;               // [8192][2048]; reused as ctx
  unsigned short* wqkvT = xb    + (size_t)MROWS * D_MODEL;     // [6144][2048]
  unsigned short* woutT = wqkvT + (size_t)NQKV * D_MODEL;      // [2048][2048]
  unsigned short* Qb    = woutT + (size_t)D_MODEL * D_MODEL;   // [64][2048][128]
  unsigned short* Kb    = Qb    + (size_t)BH * TSEQ * DHEAD;
  unsigned short* VTb   = Kb    + (size_t)BH * TSEQ * DHEAD;   // [64][128][2048]
  float2* tab = (float2*)(VTb + (size_t)BH * TSEQ * DHEAD);    // [2048][64]

  cvt_bf16<<<MROWS * D_MODEL / 2048, 256, 0, stream>>>(x, xb, MROWS * D_MODEL);
  transw<<<dim3(NQKV / 32, D_MODEL / 32), 256, 0, stream>>>(w_qkv, wqkvT, D_MODEL, NQKV);
  transw<<<dim3(D_MODEL / 32, D_MODEL / 32), 256, 0, stream>>>(w_out, woutT, D_MODEL, D_MODEL);
  rope_table<<<TSEQ, 64, 0, stream>>>(tab);
  gemm_bt<0><<<dim3(NQKV / 128, MROWS / 128), 256, 0, stream>>>(
      xb, wqkvT, b_qkv, MROWS, NQKV, D_MODEL, Qb, Kb, VTb, nullptr);
  rope_apply<<<BH * TSEQ / 4, 256, 0, stream>>>(Qb, tab);
  rope_apply<<<BH * TSEQ / 4, 256, 0, stream>>>(Kb, tab);
  attn_fwd<<<dim3(TSEQ / 64, BH), 256, 0, stream>>>(Qb, Kb, VTb, xb);
  gemm_bt<1><<<dim3(D_MODEL / 128, MROWS / 128), 256, 0, stream>>>(
      xb, woutT, b_out, MROWS, D_MODEL, D_MODEL, nullptr, nullptr, nullptr, out);
}